// Round 1
// baseline (2395.581 us; speedup 1.0000x reference)
//
#include <hip/hip_runtime.h>
#include <math.h>

#define NN 50000
#define NE 600000
#define D 128

// ---------------- zero workspace ----------------
__global__ void zero_ws(float4* __restrict__ p, int n4) {
    int i = blockIdx.x * blockDim.x + threadIdx.x;
    const int stride = gridDim.x * blockDim.x;
    const float4 z = make_float4(0.f, 0.f, 0.f, 0.f);
    for (; i < n4; i += stride) p[i] = z;
}

// ---------------- Wd = W1 - W2 ----------------
__global__ void prep_wd(const float* __restrict__ Wdisc, float* __restrict__ Wd) {
    int i = blockIdx.x * blockDim.x + threadIdx.x;
    if (i < D * D) Wd[i] = Wdisc[i] - Wdisc[i + D * D];
}

// ---------------- edge scatter: S_in[dst] += x[src]; S_out[src] += x[dst] ----------------
__global__ __launch_bounds__(256) void edge_scatter(
    const float* __restrict__ x, const int* __restrict__ ei,
    float* __restrict__ S_in, float* __restrict__ S_out,
    float* __restrict__ deg_in, float* __restrict__ deg_out)
{
    const int e = blockIdx.x * 8 + (threadIdx.x >> 5);   // 8 edges / 256-thread block
    const int lane = threadIdx.x & 31;                   // 32 lanes x float4 = 128 f32
    const int s = ei[e];
    const int d = ei[NE + e];
    const float4 vs = ((const float4*)(x + (size_t)s * D))[lane];
    const float4 vd = ((const float4*)(x + (size_t)d * D))[lane];
    float* pin  = S_in  + (size_t)d * D + lane * 4;
    float* pout = S_out + (size_t)s * D + lane * 4;
    unsafeAtomicAdd(pin + 0, vs.x);
    unsafeAtomicAdd(pin + 1, vs.y);
    unsafeAtomicAdd(pin + 2, vs.z);
    unsafeAtomicAdd(pin + 3, vs.w);
    unsafeAtomicAdd(pout + 0, vd.x);
    unsafeAtomicAdd(pout + 1, vd.y);
    unsafeAtomicAdd(pout + 2, vd.z);
    unsafeAtomicAdd(pout + 3, vd.w);
    if (lane == 0) {
        unsafeAtomicAdd(deg_in + d, 1.0f);
        unsafeAtomicAdd(deg_out + s, 1.0f);
    }
}

// ---------------- fused node kernel ----------------
// per node: h_self = x@W_self + b_self
//           t2     = x@W2
//           h_in   = S_in @Wd + deg_in *(t2 + b_disc)
//           h_out  = S_out@Wd + deg_out*(t2 + b_disc)
// then 3-way attention softmax over tanh(rep@W_a1 + b_a1)@W_a2
__global__ __launch_bounds__(512) void node_kernel(
    const float* __restrict__ x,
    const float* __restrict__ S_in, const float* __restrict__ S_out,
    const float* __restrict__ deg_in, const float* __restrict__ deg_out,
    const float* __restrict__ W_self, const float* __restrict__ b_self,
    const float* __restrict__ Wd, const float* __restrict__ W2,
    const float* __restrict__ b_disc,
    const float* __restrict__ W_a1, const float* __restrict__ b_a1,
    const float* __restrict__ W_a2,
    float* __restrict__ out)
{
    __shared__ float sWs [32][128];
    __shared__ float sWdl[32][128];
    __shared__ float sW2 [32][128];
    __shared__ float sRow[8][3][132];   // x / S_in / S_out rows, then reps; +4 pad
    __shared__ float sWa1[128][16];
    __shared__ float sWa2[16];
    __shared__ float sBa1[16];
    __shared__ float sAtt[8][3];

    const int tid  = threadIdx.x;
    const int wave = tid >> 6;
    const int lane = tid & 63;
    const int node = blockIdx.x * 8 + wave;   // grid = 6250 -> exactly 50000 nodes

    // stage attention weights (2048 floats = 512 float4)
    ((float4*)sWa1)[tid] = ((const float4*)W_a1)[tid];
    if (tid < 16) { sWa2[tid] = W_a2[tid]; sBa1[tid] = b_a1[tid]; }

    // stage this wave's node rows (float2 per lane, 64*2 = 128)
    ((float2*)sRow[wave][0])[lane] = ((const float2*)(x     + (size_t)node * D))[lane];
    ((float2*)sRow[wave][1])[lane] = ((const float2*)(S_in  + (size_t)node * D))[lane];
    ((float2*)sRow[wave][2])[lane] = ((const float2*)(S_out + (size_t)node * D))[lane];

    float hs0=0.f,hs1=0.f,t20=0.f,t21=0.f,hi0=0.f,hi1=0.f,ho0=0.f,ho1=0.f;

    for (int k0 = 0; k0 < D; k0 += 32) {
        __syncthreads();
        {   // cooperative tile load: 32x128 per matrix, 8 floats/thread
            const int kk = tid >> 4;
            const int jj = (tid & 15) * 8;
            const float* gs = W_self + (size_t)(k0 + kk) * D + jj;
            const float* gd = Wd     + (size_t)(k0 + kk) * D + jj;
            const float* g2 = W2     + (size_t)(k0 + kk) * D + jj;
            *(float4*)&sWs [kk][jj]     = *(const float4*)(gs);
            *(float4*)&sWs [kk][jj + 4] = *(const float4*)(gs + 4);
            *(float4*)&sWdl[kk][jj]     = *(const float4*)(gd);
            *(float4*)&sWdl[kk][jj + 4] = *(const float4*)(gd + 4);
            *(float4*)&sW2 [kk][jj]     = *(const float4*)(g2);
            *(float4*)&sW2 [kk][jj + 4] = *(const float4*)(g2 + 4);
        }
        __syncthreads();
        const float* rx = sRow[wave][0] + k0;
        const float* ri = sRow[wave][1] + k0;
        const float* ro = sRow[wave][2] + k0;
        #pragma unroll
        for (int k = 0; k < 32; ++k) {
            const float xv  = rx[k];
            const float siv = ri[k];
            const float sov = ro[k];
            const float2 ws = *(const float2*)&sWs [k][2 * lane];
            const float2 wd = *(const float2*)&sWdl[k][2 * lane];
            const float2 w2 = *(const float2*)&sW2 [k][2 * lane];
            hs0 += xv  * ws.x;  hs1 += xv  * ws.y;
            t20 += xv  * w2.x;  t21 += xv  * w2.y;
            hi0 += siv * wd.x;  hi1 += siv * wd.y;
            ho0 += sov * wd.x;  ho1 += sov * wd.y;
        }
    }

    const int f0 = 2 * lane, f1 = f0 + 1;
    const float di = deg_in[node], dO = deg_out[node];
    const float bd0 = b_disc[f0], bd1 = b_disc[f1];
    const float r0a = hs0 + b_self[f0],      r0b = hs1 + b_self[f1];
    const float r1a = hi0 + di * (t20 + bd0), r1b = hi1 + di * (t21 + bd1);
    const float r2a = ho0 + dO * (t20 + bd0), r2b = ho1 + dO * (t21 + bd1);

    __syncthreads();   // k-loop reads of sRow done everywhere
    sRow[wave][0][f0] = r0a;  sRow[wave][0][f1] = r0b;
    sRow[wave][1][f0] = r1a;  sRow[wave][1][f1] = r1b;
    sRow[wave][2][f0] = r2a;  sRow[wave][2][f1] = r2b;
    __syncthreads();

    if (lane < 48) {
        const int r = lane >> 4, h = lane & 15;
        const float* rp = sRow[wave][r];
        float acc = sBa1[h];
        #pragma unroll 8
        for (int j = 0; j < 128; ++j) acc += rp[j] * sWa1[j][h];
        float part = tanhf(acc) * sWa2[h];
        part += __shfl_down(part, 8, 16);
        part += __shfl_down(part, 4, 16);
        part += __shfl_down(part, 2, 16);
        part += __shfl_down(part, 1, 16);
        if (h == 0) sAtt[wave][r] = part;
    }
    __syncthreads();

    const float l0 = sAtt[wave][0], l1 = sAtt[wave][1], l2 = sAtt[wave][2];
    const float m  = fmaxf(l0, fmaxf(l1, l2));
    const float e0 = __expf(l0 - m), e1 = __expf(l1 - m), e2 = __expf(l2 - m);
    const float inv = 1.0f / (e0 + e1 + e2);
    const float a0 = e0 * inv, a1 = e1 * inv, a2 = e2 * inv;
    const float o0 = a0 * r0a + a1 * r1a + a2 * r2a;
    const float o1 = a0 * r0b + a1 * r1b + a2 * r2b;
    *(float2*)(out + (size_t)node * D + f0) = make_float2(o0, o1);
}

extern "C" void kernel_launch(void* const* d_in, const int* in_sizes, int n_in,
                              void* d_out, int out_size, void* d_ws, size_t ws_size,
                              hipStream_t stream) {
    const float* x      = (const float*)d_in[0];
    const int*   ei     = (const int*)  d_in[1];
    const float* W_self = (const float*)d_in[2];
    const float* b_self = (const float*)d_in[3];
    const float* W_disc = (const float*)d_in[4];
    const float* b_disc = (const float*)d_in[5];
    const float* W_a1   = (const float*)d_in[6];
    const float* b_a1   = (const float*)d_in[7];
    const float* W_a2   = (const float*)d_in[8];
    float* out = (float*)d_out;

    char* ws = (char*)d_ws;
    float* S_in    = (float*)(ws);                 // 50000*128*4 = 25,600,000 B
    float* S_out   = (float*)(ws + 25600000);      // 25,600,000 B
    float* deg_in  = (float*)(ws + 51200000);      // 200,000 B
    float* deg_out = (float*)(ws + 51400000);      // 200,000 B
    float* Wd      = (float*)(ws + 51600000);      // 65,536 B
    const float* W2 = W_disc + D * D;

    zero_ws<<<2048, 256, 0, stream>>>((float4*)ws, 51600000 / 16);
    prep_wd<<<64, 256, 0, stream>>>(W_disc, Wd);
    edge_scatter<<<75000, 256, 0, stream>>>(x, ei, S_in, S_out, deg_in, deg_out);
    node_kernel<<<6250, 512, 0, stream>>>(x, S_in, S_out, deg_in, deg_out,
                                          W_self, b_self, Wd, W2, b_disc,
                                          W_a1, b_a1, W_a2, out);
}

// Round 2
// 711.124 us; speedup vs baseline: 3.3687x; 3.3687x over previous
//
#include <hip/hip_runtime.h>
#include <math.h>

#define NN 50000
#define NE 600000
#define D 128
#define SCAN_T 1024
#define CHUNK 49   // ceil(50000/1024)

// ---------------- zero (small: histogram counters) ----------------
__global__ void zero_ws(float4* __restrict__ p, int n4) {
    int i = blockIdx.x * blockDim.x + threadIdx.x;
    const int stride = gridDim.x * blockDim.x;
    const float4 z = make_float4(0.f, 0.f, 0.f, 0.f);
    for (; i < n4; i += stride) p[i] = z;
}

// ---------------- Wd = W1 - W2 ----------------
__global__ void prep_wd(const float* __restrict__ Wdisc, float* __restrict__ Wd) {
    int i = blockIdx.x * blockDim.x + threadIdx.x;
    if (i < D * D) Wd[i] = Wdisc[i] - Wdisc[i + D * D];
}

// ---------------- degree histogram (int atomics on L2-resident counters) ----------------
__global__ __launch_bounds__(256) void hist_kernel(const int* __restrict__ ei,
                                                   int* __restrict__ cnt_in,
                                                   int* __restrict__ cnt_out) {
    const int e = blockIdx.x * blockDim.x + threadIdx.x;
    if (e < NE) {
        atomicAdd(&cnt_out[ei[e]], 1);        // src out-degree
        atomicAdd(&cnt_in[ei[NE + e]], 1);    // dst in-degree
    }
}

// ---------------- exclusive scan of 50000 counters (one block per array) ----------------
// cnt arrays are aliased with the cursor arrays: after scan, cur[i] = off[i].
__global__ __launch_bounds__(SCAN_T) void scan_kernel(int* __restrict__ cnt_in,
                                                      int* __restrict__ cnt_out,
                                                      int* __restrict__ off_in,
                                                      int* __restrict__ off_out) {
    int* cnt = (blockIdx.x == 0) ? cnt_in : cnt_out;   // read counts, rewrite as cursors
    int* off = (blockIdx.x == 0) ? off_in : off_out;
    __shared__ int sums[SCAN_T];
    const int t = threadIdx.x;
    const int lo = t * CHUNK;
    const int hi = min(lo + CHUNK, NN);
    int s = 0;
    for (int i = lo; i < hi; ++i) s += cnt[i];
    sums[t] = s;
    __syncthreads();
    for (int d = 1; d < SCAN_T; d <<= 1) {   // Hillis-Steele inclusive scan
        int v = (t >= d) ? sums[t - d] : 0;
        __syncthreads();
        sums[t] += v;
        __syncthreads();
    }
    int run = (t == 0) ? 0 : sums[t - 1];    // exclusive prefix of this chunk
    for (int i = lo; i < hi; ++i) {
        const int c = cnt[i];                // read BEFORE overwrite (aliased)
        off[i] = run;
        cnt[i] = run;                        // cursor init
        run += c;
    }
    if (t == SCAN_T - 1) off[NN] = run;      // total = NE
}

// ---------------- scatter edge endpoints into CSR lists ----------------
__global__ __launch_bounds__(256) void scatter_kernel(const int* __restrict__ ei,
                                                      int* __restrict__ cur_in,
                                                      int* __restrict__ cur_out,
                                                      int* __restrict__ lst_in,
                                                      int* __restrict__ lst_out) {
    const int e = blockIdx.x * blockDim.x + threadIdx.x;
    if (e < NE) {
        const int s = ei[e];
        const int d = ei[NE + e];
        lst_in [atomicAdd(&cur_in [d], 1)] = s;   // in-neighbors of d
        lst_out[atomicAdd(&cur_out[s], 1)] = d;   // out-neighbors of s
    }
}

// ---------------- fused gather + node kernel ----------------
// per node: S_in = sum x[src in-nbrs], S_out = sum x[dst out-nbrs]  (register gather)
//           h_self = x@W_self + b_self ; t2 = x@W2
//           h_in   = S_in @Wd + deg_in *(t2 + b_disc)
//           h_out  = S_out@Wd + deg_out*(t2 + b_disc)
// then 3-way attention softmax over tanh(rep@W_a1 + b_a1)@W_a2
__global__ __launch_bounds__(512) void node_kernel(
    const float* __restrict__ x,
    const int* __restrict__ off_in, const int* __restrict__ off_out,
    const int* __restrict__ lst_in, const int* __restrict__ lst_out,
    const float* __restrict__ W_self, const float* __restrict__ b_self,
    const float* __restrict__ Wd, const float* __restrict__ W2,
    const float* __restrict__ b_disc,
    const float* __restrict__ W_a1, const float* __restrict__ b_a1,
    const float* __restrict__ W_a2,
    float* __restrict__ out)
{
    __shared__ float sWs [32][128];
    __shared__ float sWdl[32][128];
    __shared__ float sW2 [32][128];
    __shared__ float sRow[8][3][132];   // x / S_in / S_out rows, then reps; +4 pad
    __shared__ float sWa1[128][16];
    __shared__ float sWa2[16];
    __shared__ float sBa1[16];
    __shared__ float sAtt[8][3];

    const int tid  = threadIdx.x;
    const int wave = tid >> 6;
    const int lane = tid & 63;
    const int node = blockIdx.x * 8 + wave;   // grid = 6250 -> exactly 50000 nodes

    // stage attention weights (2048 floats = 512 float4)
    ((float4*)sWa1)[tid] = ((const float4*)W_a1)[tid];
    if (tid < 16) { sWa2[tid] = W_a2[tid]; sBa1[tid] = b_a1[tid]; }

    // ---- gather: coalesced 512B/wave row reads of L3-resident x ----
    const int b_i = off_in[node],  e_i = off_in[node + 1];
    const int b_o = off_out[node], e_o = off_out[node + 1];
    float si0 = 0.f, si1 = 0.f, so0 = 0.f, so1 = 0.f;
    {
        int p = b_i;
        int src = (p < e_i) ? lst_in[p] : 0;
        while (p < e_i) {
            const int nxt = (p + 1 < e_i) ? lst_in[p + 1] : 0;  // index lookahead
            const float2 v = ((const float2*)(x + (size_t)src * D))[lane];
            si0 += v.x; si1 += v.y;
            src = nxt; ++p;
        }
    }
    {
        int p = b_o;
        int dn = (p < e_o) ? lst_out[p] : 0;
        while (p < e_o) {
            const int nxt = (p + 1 < e_o) ? lst_out[p + 1] : 0;
            const float2 v = ((const float2*)(x + (size_t)dn * D))[lane];
            so0 += v.x; so1 += v.y;
            dn = nxt; ++p;
        }
    }

    // stage this wave's rows
    ((float2*)sRow[wave][0])[lane] = ((const float2*)(x + (size_t)node * D))[lane];
    ((float2*)sRow[wave][1])[lane] = make_float2(si0, si1);
    ((float2*)sRow[wave][2])[lane] = make_float2(so0, so1);

    float hs0=0.f,hs1=0.f,t20=0.f,t21=0.f,hi0=0.f,hi1=0.f,ho0=0.f,ho1=0.f;

    for (int k0 = 0; k0 < D; k0 += 32) {
        __syncthreads();
        {   // cooperative tile load: 32x128 per matrix, 8 floats/thread
            const int kk = tid >> 4;
            const int jj = (tid & 15) * 8;
            const float* gs = W_self + (size_t)(k0 + kk) * D + jj;
            const float* gd = Wd     + (size_t)(k0 + kk) * D + jj;
            const float* g2 = W2     + (size_t)(k0 + kk) * D + jj;
            *(float4*)&sWs [kk][jj]     = *(const float4*)(gs);
            *(float4*)&sWs [kk][jj + 4] = *(const float4*)(gs + 4);
            *(float4*)&sWdl[kk][jj]     = *(const float4*)(gd);
            *(float4*)&sWdl[kk][jj + 4] = *(const float4*)(gd + 4);
            *(float4*)&sW2 [kk][jj]     = *(const float4*)(g2);
            *(float4*)&sW2 [kk][jj + 4] = *(const float4*)(g2 + 4);
        }
        __syncthreads();
        const float* rx = sRow[wave][0] + k0;
        const float* ri = sRow[wave][1] + k0;
        const float* ro = sRow[wave][2] + k0;
        #pragma unroll
        for (int k = 0; k < 32; ++k) {
            const float xv  = rx[k];
            const float siv = ri[k];
            const float sov = ro[k];
            const float2 ws = *(const float2*)&sWs [k][2 * lane];
            const float2 wd = *(const float2*)&sWdl[k][2 * lane];
            const float2 w2 = *(const float2*)&sW2 [k][2 * lane];
            hs0 += xv  * ws.x;  hs1 += xv  * ws.y;
            t20 += xv  * w2.x;  t21 += xv  * w2.y;
            hi0 += siv * wd.x;  hi1 += siv * wd.y;
            ho0 += sov * wd.x;  ho1 += sov * wd.y;
        }
    }

    const int f0 = 2 * lane, f1 = f0 + 1;
    const float di = (float)(e_i - b_i);
    const float dO = (float)(e_o - b_o);
    const float bd0 = b_disc[f0], bd1 = b_disc[f1];
    const float r0a = hs0 + b_self[f0],       r0b = hs1 + b_self[f1];
    const float r1a = hi0 + di * (t20 + bd0), r1b = hi1 + di * (t21 + bd1);
    const float r2a = ho0 + dO * (t20 + bd0), r2b = ho1 + dO * (t21 + bd1);

    __syncthreads();   // k-loop reads of sRow done everywhere
    sRow[wave][0][f0] = r0a;  sRow[wave][0][f1] = r0b;
    sRow[wave][1][f0] = r1a;  sRow[wave][1][f1] = r1b;
    sRow[wave][2][f0] = r2a;  sRow[wave][2][f1] = r2b;
    __syncthreads();

    if (lane < 48) {
        const int r = lane >> 4, h = lane & 15;
        const float* rp = sRow[wave][r];
        float acc = sBa1[h];
        #pragma unroll 8
        for (int j = 0; j < 128; ++j) acc += rp[j] * sWa1[j][h];
        float part = tanhf(acc) * sWa2[h];
        part += __shfl_down(part, 8, 16);
        part += __shfl_down(part, 4, 16);
        part += __shfl_down(part, 2, 16);
        part += __shfl_down(part, 1, 16);
        if (h == 0) sAtt[wave][r] = part;
    }
    __syncthreads();

    const float l0 = sAtt[wave][0], l1 = sAtt[wave][1], l2 = sAtt[wave][2];
    const float m  = fmaxf(l0, fmaxf(l1, l2));
    const float e0 = __expf(l0 - m), e1 = __expf(l1 - m), e2 = __expf(l2 - m);
    const float inv = 1.0f / (e0 + e1 + e2);
    const float a0 = e0 * inv, a1 = e1 * inv, a2 = e2 * inv;
    const float o0 = a0 * r0a + a1 * r1a + a2 * r2a;
    const float o1 = a0 * r0b + a1 * r1b + a2 * r2b;
    *(float2*)(out + (size_t)node * D + f0) = make_float2(o0, o1);
}

extern "C" void kernel_launch(void* const* d_in, const int* in_sizes, int n_in,
                              void* d_out, int out_size, void* d_ws, size_t ws_size,
                              hipStream_t stream) {
    const float* x      = (const float*)d_in[0];
    const int*   ei     = (const int*)  d_in[1];
    const float* W_self = (const float*)d_in[2];
    const float* b_self = (const float*)d_in[3];
    const float* W_disc = (const float*)d_in[4];
    const float* b_disc = (const float*)d_in[5];
    const float* W_a1   = (const float*)d_in[6];
    const float* b_a1   = (const float*)d_in[7];
    const float* W_a2   = (const float*)d_in[8];
    float* out = (float*)d_out;

    // workspace layout (bytes)
    char* ws = (char*)d_ws;
    int* cnt_in  = (int*)(ws);             // 50000 ints; aliased as cur_in after scan
    int* cnt_out = (int*)(ws + 200000);    // 50000 ints; aliased as cur_out
    int* off_in  = (int*)(ws + 400000);    // 50001 ints (reserve 200016 B)
    int* off_out = (int*)(ws + 600016);    // 50001 ints
    int* lst_in  = (int*)(ws + 800032);    // 600000 ints
    int* lst_out = (int*)(ws + 3200032);   // 600000 ints
    float* Wd    = (float*)(ws + 5600032); // 16384 floats (16B aligned)
    const float* W2 = W_disc + D * D;

    zero_ws<<<98, 256, 0, stream>>>((float4*)ws, 400000 / 16);   // zero both cnt arrays
    prep_wd<<<64, 256, 0, stream>>>(W_disc, Wd);
    hist_kernel<<<(NE + 255) / 256, 256, 0, stream>>>(ei, cnt_in, cnt_out);
    scan_kernel<<<2, SCAN_T, 0, stream>>>(cnt_in, cnt_out, off_in, off_out);
    scatter_kernel<<<(NE + 255) / 256, 256, 0, stream>>>(ei, cnt_in, cnt_out, lst_in, lst_out);
    node_kernel<<<6250, 512, 0, stream>>>(x, off_in, off_out, lst_in, lst_out,
                                          W_self, b_self, Wd, W2, b_disc,
                                          W_a1, b_a1, W_a2, out);
}